// Round 13
// baseline (649.428 us; speedup 1.0000x reference)
//
#include <hip/hip_runtime.h>
#include <hip/hip_bf16.h>

// DecoderRNN: attention degenerate (enc seq len == 1 -> awe == gate*features).
// R13 = R9 (best: 598us) + B-stationary final GEMM (from R12's proven consumer,
//   run STANDALONE after recur: no flags, no sc-bits, plain cached loads).
//   Each outgemm block: stage one 128KB Wfct n-tile into swizzled LDS ONCE,
//   then loop t=0..19 (A = 64KB hs slice, L2-broadcast) -> replaces the
//   ~200us K-restaging gemm2<1> with ~70-90us. recur kept verbatim (297us)
//   except hs layout -> [t*64+b][512] (contiguous A per t).

#define VV 50257
#define VP 50304    // 786*64
#define TT 20
#define NWRK 32
#define NTILES 6288 // 786 * 8 transpose tiles

typedef __attribute__((ext_vector_type(4))) float f32x4;
typedef __attribute__((ext_vector_type(8))) short bf16x8;

#define MFMA(a,b,c) __builtin_amdgcn_mfma_f32_16x16x32_bf16((a),(b),(c),0,0,0)

__device__ __forceinline__ unsigned short f2bf(float f){
  union { float f; unsigned int u; } v; v.f = f;
  unsigned int u = v.u;
  return (unsigned short)((u + 0x7FFFu + ((u >> 16) & 1u)) >> 16);
}
__device__ __forceinline__ float sigf(float x){ return 1.f/(1.f + expf(-x)); }

__device__ __forceinline__ void gload_lds16(const unsigned short* g, unsigned short* l){
  __builtin_amdgcn_global_load_lds(
      (const __attribute__((address_space(1))) unsigned int*)g,
      (__attribute__((address_space(3))) unsigned int*)l, 16, 0, 0);
}

// ---- device-coherent accessors (worker fabric; sc0 sc1 everywhere) ----
__device__ __forceinline__ void co_load16(bf16x8* d, const unsigned short* p){
  asm volatile("global_load_dwordx4 %0, %1, off sc0 sc1" : "=v"(*d) : "v"(p));
}
__device__ __forceinline__ void co_store2(unsigned short* p, unsigned short v){
  asm volatile("global_store_short %0, %1, off sc0 sc1" :: "v"(p), "v"(v) : "memory");
}
__device__ __forceinline__ unsigned int co_load_u32(const unsigned int* p){
  unsigned int r;
  asm volatile("global_load_dword %0, %1, off sc0 sc1\n\ts_waitcnt vmcnt(0)"
               : "=v"(r) : "v"(p) : "memory");
  return r;
}
__device__ __forceinline__ void co_store_u32(unsigned int* p, unsigned int v){
  asm volatile("global_store_dword %0, %1, off sc0 sc1" :: "v"(p), "v"(v) : "memory");
}

// flag barrier among the NWRK workers
__device__ __forceinline__ void gbar(unsigned int* flags, int widx, unsigned target){
  asm volatile("s_waitcnt vmcnt(0)" ::: "memory");
  __syncthreads();
  if(threadIdx.x == 0){
    co_store_u32(flags + widx, target);
  }
  if(threadIdx.x < 64){
    const unsigned int* p = flags + (threadIdx.x & 31);
    for(;;){
      unsigned v = co_load_u32(p);
      if(__all((int)(v >= target))) break;
      __builtin_amdgcn_s_sleep(1);
    }
  }
  __syncthreads();
}

// ---------- merged prep kernel ----------
// [0,2048): cvt_weights | [2048,2112): Wbeta^T | [2112,3392): emb | [3392,3456): h0/c0
__global__ __launch_bounds__(256) void prep(const float* __restrict__ Wih,
    const float* __restrict__ Whh, unsigned short* __restrict__ Wcomb,
    unsigned short* __restrict__ We,
    const float* __restrict__ Wbeta, unsigned short* __restrict__ Wbt,
    const float* __restrict__ feat, const float* __restrict__ emb,
    const int* __restrict__ cap, unsigned short* __restrict__ EmbMat,
    const float* __restrict__ Whi, const float* __restrict__ bhi,
    const float* __restrict__ Wci, const float* __restrict__ bci,
    unsigned short* __restrict__ xbuf, float* __restrict__ cbuf){
  __shared__ float tile[64][65];
  const int blk = blockIdx.x, tid = threadIdx.x;
  if(blk < 2048){
    int j = blk;
    for(int q=0;q<4;q++){ int k = tid + 256*q;
      float v = (k < 512) ? Whh[j*512 + k] : Wih[j*1024 + k];
      Wcomb[(size_t)j*1024 + k] = f2bf(v); }
    for(int q=0;q<2;q++){ int k = tid + 256*q;
      We[(size_t)j*512 + k] = f2bf(Wih[j*1024 + k]); }
  } else if(blk < 2112){
    int tb = blk - 2048;
    int c0 = (tb & 7)*64, r0 = (tb >> 3)*64;
    int tx = tid & 63, ty = tid >> 6;
    for(int i=0;i<16;i++){
      int r = ty + i*4;
      tile[r][tx] = Wbeta[(size_t)(r0+r)*512 + c0 + tx];
    }
    __syncthreads();
    for(int i=0;i<16;i++){
      int cl = ty + i*4;
      Wbt[(size_t)(c0+cl)*512 + r0 + tx] = f2bf(tile[tx][cl]);
    }
  } else if(blk < 3392){
    int m = blk - 2112; int t = m >> 6, b = m & 63;
    const float* src = (t == 0) ? (feat + b*512) : (emb + (size_t)cap[b*19 + (t-1)]*512);
    for(int q=0;q<2;q++){ int k = tid + 256*q;
      EmbMat[(size_t)m*512 + k] = f2bf(src[k]); }
  } else {
    int b = blk - 3392;
    float ah0 = bhi[tid], ah1 = bhi[tid+256];
    float ac0 = bci[tid], ac1 = bci[tid+256];
    for(int k=0;k<512;k++){
      float f = feat[b*512 + k];
      ah0 += f * Whi[k*512 + tid];     ah1 += f * Whi[k*512 + tid + 256];
      ac0 += f * Wci[k*512 + tid];     ac1 += f * Wci[k*512 + tid + 256];
    }
    xbuf[b*512 + tid] = f2bf(ah0);  xbuf[b*512 + tid + 256] = f2bf(ah1);
    cbuf[b*512 + tid] = ac0;        cbuf[b*512 + tid + 256] = ac1;
  }
}

// ---------- 128x128 NT MFMA GEMM, K=512: E4 (gate-minor) ----------
__global__ __launch_bounds__(256) void gemmE(const unsigned short* __restrict__ Abf,
    const unsigned short* __restrict__ Bbf, const float* __restrict__ bias1,
    const float* __restrict__ bias2, float* __restrict__ Cout, int MT){
  __shared__ __align__(16) unsigned short As[128*64];
  __shared__ __align__(16) unsigned short Bs[128*64];
  const int nwg = gridDim.x;
  const int id = blockIdx.x;
  const int q = nwg >> 3, rr = nwg & 7;
  const int xcd = id & 7, pos = id >> 3;
  const int work = (xcd < rr) ? (xcd*(q+1) + pos) : (rr*(q+1) + (xcd-rr)*q + pos);
  const int m0 = (work % MT) * 128;
  const int n0 = (work / MT) * 128;
  const int tid = threadIdx.x, lane = tid & 63, w = tid >> 6;
  const int wr = w >> 1, wc = w & 1;
  const int lrow = lane >> 3, lcol = (lane & 7) * 8;
  const int l15 = lane & 15, lhi = lane >> 4;

  f32x4 acc[4][4];
#pragma unroll
  for(int i=0;i<4;i++)
#pragma unroll
    for(int j=0;j<4;j++) acc[i][j] = f32x4{0.f,0.f,0.f,0.f};

  for(int k0=0;k0<512;k0+=64){
    __syncthreads();
#pragma unroll
    for(int i=0;i<4;i++){
      int c = w*4 + i;
      int row = c*8 + lrow;
      gload_lds16(Abf + (size_t)(m0+row)*512 + k0 + lcol, As + c*512);
      gload_lds16(Bbf + (size_t)(n0+row)*512 + k0 + lcol, Bs + c*512);
    }
    asm volatile("s_waitcnt vmcnt(0)" ::: "memory");
    __syncthreads();
#pragma unroll
    for(int kk=0;kk<64;kk+=32){
      bf16x8 af[4], bfv[4];
#pragma unroll
      for(int mf=0;mf<4;mf++)
        af[mf] = *(const bf16x8*)(As + (wr*64 + mf*16 + l15)*64 + kk + lhi*8);
#pragma unroll
      for(int nf=0;nf<4;nf++)
        bfv[nf] = *(const bf16x8*)(Bs + (wc*64 + nf*16 + l15)*64 + kk + lhi*8);
#pragma unroll
      for(int mf=0;mf<4;mf++)
#pragma unroll
        for(int nf=0;nf<4;nf++)
          acc[mf][nf] = MFMA(af[mf], bfv[nf], acc[mf][nf]);
    }
  }
#pragma unroll
  for(int mf=0;mf<4;mf++)
#pragma unroll
    for(int nf=0;nf<4;nf++){
      int n = n0 + wc*64 + nf*16 + l15;
#pragma unroll
      for(int r=0;r<4;r++){
        int m = m0 + wr*64 + mf*16 + lhi*4 + r;
        int gate = n >> 9, col = n & 511;
        Cout[((size_t)m*512 + col)*4 + gate] = acc[mf][nf][r] + bias1[n] + bias2[n];
      }
    }
}

// ---------- single-XCD persistent recurrence + ticketed Wfc transpose (R9) ----------
// ctrs: [0]=worker tk, [16]=tp tk, [32..63]=flags
__global__ __launch_bounds__(256) void recur(
    const unsigned short* __restrict__ Wcomb,  // [2048][1024] bf16
    const unsigned short* __restrict__ Wbt,    // [512][512] bf16 (W_beta^T)
    const float* __restrict__ bbeta,
    const float* __restrict__ feat,            // [64][512] f32
    const float* __restrict__ E4,              // gate-minor f32
    const float* __restrict__ c0,
    const int* __restrict__ lens,
    unsigned short* xbuf,                      // [64][512] bf16 h
    unsigned short* awbuf,                     // [64][512] bf16 awe
    unsigned short* __restrict__ hs,           // [t*64+b][512] bf16
    unsigned int* ctrs,
    const float* __restrict__ Wfc, unsigned short* __restrict__ Wfct){
  extern __shared__ char LDS[];
  char* WCb = LDS;            // 131072
  char* WBb = LDS + 131072;   // 16384
  int* lsh = (int*)LDS;
  const int tid = threadIdx.x;

  if(tid == 0){
    unsigned xcc = 99;
    asm volatile("s_getreg_b32 %0, hwreg(HW_REG_XCC_ID)" : "=s"(xcc));
    unsigned my = 0xffffffffu;
    if(xcc == 0) my = atomicAdd(&ctrs[0], 1u);
    lsh[0] = (my < NWRK) ? 1 : 0;
    lsh[1] = (int)my;
  }
  __syncthreads();
  const int iswork = lsh[0];
  const int widx = lsh[1];
  __syncthreads();

  if(!iswork){
    // ---- Wfc transpose via ticket ----
    float (*tile)[65] = (float(*)[65])LDS;
    int tx = tid & 63, ty = tid >> 6;
    for(;;){
      __syncthreads();
      if(tid == 0) lsh[0] = (int)atomicAdd(&ctrs[16], 1u);
      __syncthreads();
      int tb = lsh[0];
      __syncthreads();
      if(tb >= NTILES) return;
      int c0t = (tb % 786)*64, r0 = (tb / 786)*64;
      for(int i=0;i<16;i++){
        int r = ty + i*4; int sc = c0t + tx;
        tile[r][tx] = (sc < VV) ? Wfc[(size_t)(r0+r)*VV + sc] : 0.f;
      }
      __syncthreads();
      for(int i=0;i<16;i++){
        int cl = ty + i*4;
        Wfct[(size_t)(c0t+cl)*512 + r0 + tx] = f2bf(tile[tx][cl]);
      }
    }
  }

  // ---- worker ----
  const int lane = tid & 63, w = tid >> 6;
  const int l15 = lane & 15, lhi = lane >> 4;
  const int jj0 = widx * 16;
  const int jj = jj0 + l15;
  const int arow = w*16 + l15;
  unsigned int* flags = &ctrs[32];

  for(int cid = tid; cid < 8192; cid += 256){
    int gr = cid >> 7, cc = cid & 127;
    size_t g = (size_t)(gr >> 4)*512 + jj0 + (gr & 15);
    bf16x8 v = *(const bf16x8*)(Wcomb + g*1024 + cc*8);
    *(bf16x8*)(WCb + gr*2048 + ((cc*16) ^ ((gr & 7) << 4))) = v;
  }
  for(int cid = tid; cid < 1024; cid += 256){
    int r = cid >> 6, cc = cid & 63;
    bf16x8 v = *(const bf16x8*)(Wbt + (size_t)(jj0 + r)*512 + cc*8);
    *(bf16x8*)(WBb + r*1024 + ((cc*16) ^ ((r & 7) << 4))) = v;
  }

  float c_reg[4], fe[4]; int ln[4]; unsigned short hold[4];
#pragma unroll
  for(int r=0;r<4;r++){
    int b = w*16 + lhi*4 + r;
    c_reg[r] = c0[b*512 + jj];
    fe[r]    = feat[b*512 + jj];
    ln[r]    = lens[b];
    hold[r]  = xbuf[b*512 + jj];
  }
  const float bb = bbeta[jj];
  const unsigned short* pAx = xbuf  + (size_t)arow*512 + lhi*8;
  const unsigned short* pAw = awbuf + (size_t)arow*512 + lhi*8;
  __syncthreads();

  for(int t=0;t<TT;t++){
    // E4 prefetch
    f32x4 e4v[4];
#pragma unroll
    for(int r=0;r<4;r++){
      int b = w*16 + lhi*4 + r;
      e4v[r] = *(const f32x4*)(E4 + (((size_t)(t*64 + b))*512 + jj)*4);
    }
    // ---- phase 1: h -> beta + gates-h ----
    bf16x8 a[16];
#pragma unroll
    for(int i=0;i<16;i++) co_load16(&a[i], pAx + i*32);
    asm volatile("s_waitcnt vmcnt(0)" ::: "memory");
    __builtin_amdgcn_sched_barrier(0);

    f32x4 acca = f32x4{0.f,0.f,0.f,0.f};
    f32x4 accg[4];
#pragma unroll
    for(int i=0;i<4;i++) accg[i] = f32x4{0.f,0.f,0.f,0.f};
#pragma unroll
    for(int i=0;i<16;i++){
      int kb2 = i*64 + lhi*16;
      bf16x8 wb = *(const bf16x8*)(WBb + l15*1024 + (kb2 ^ ((l15 & 7) << 4)));
      acca = MFMA(a[i], wb, acca);
#pragma unroll
      for(int nf=0; nf<4; nf++){
        int gr = nf*16 + l15;
        bf16x8 wg = *(const bf16x8*)(WCb + gr*2048 + (kb2 ^ ((gr & 7) << 4)));
        accg[nf] = MFMA(a[i], wg, accg[nf]);
      }
    }
#pragma unroll
    for(int r=0;r<4;r++){
      int b = w*16 + lhi*4 + r;
      float g = sigf(acca[r] + bb);
      co_store2(awbuf + b*512 + jj, f2bf(g * fe[r]));
    }
    gbar(flags, widx, (unsigned)(2*t+1));

    // ---- phase 2: awe -> gates-awe ----
#pragma unroll
    for(int i=0;i<16;i++) co_load16(&a[i], pAw + i*32);
    asm volatile("s_waitcnt vmcnt(0)" ::: "memory");
    __builtin_amdgcn_sched_barrier(0);
#pragma unroll
    for(int i=0;i<16;i++){
      int kb2 = 1024 + i*64 + lhi*16;
#pragma unroll
      for(int nf=0; nf<4; nf++){
        int gr = nf*16 + l15;
        bf16x8 wg = *(const bf16x8*)(WCb + gr*2048 + (kb2 ^ ((gr & 7) << 4)));
        accg[nf] = MFMA(a[i], wg, accg[nf]);
      }
    }

    // ---- fused LSTM epilogue ----
#pragma unroll
    for(int r=0;r<4;r++){
      int b = w*16 + lhi*4 + r;
      float iv = sigf(accg[0][r] + e4v[r][0]);
      float fv = sigf(accg[1][r] + e4v[r][1]);
      float gv = tanhf(accg[2][r] + e4v[r][2]);
      float ov = sigf(accg[3][r] + e4v[r][3]);
      float cn = fv*c_reg[r] + iv*gv;
      float hn = ov * tanhf(cn);
      bool valid = t < ln[r];
      if(valid) c_reg[r] = cn;
      unsigned short hb = valid ? f2bf(hn) : hold[r];
      hold[r] = hb;
      hs[((size_t)(t*64 + b))*512 + jj] = hb;     // plain store; outgemm is a later kernel
      co_store2(xbuf + b*512 + jj, hb);
    }
    if(t < TT-1) gbar(flags, widx, (unsigned)(2*t+2));
  }
}

// ---------- B-stationary preds GEMM: block = one n-tile, loops all t ----------
// Stage 128KB Wfct tile -> swizzled LDS once; per t: A = hs[t*64 ..][512]
// (plain cached loads, L2-broadcast), 128 MFMA/wave, aligned-run epilogue.
__global__ __launch_bounds__(256) void outgemm(
    const unsigned short* __restrict__ hs,     // [t*64+b][512] bf16
    const unsigned short* __restrict__ Wfct,   // [VP][512] bf16
    const float* __restrict__ bfc, const int* __restrict__ lens,
    float* __restrict__ out){
  extern __shared__ char LDS[];
  unsigned short* Bs = (unsigned short*)LDS;    // 131072 swizzled
  float* et = (float*)(LDS + 131072);           // 16384 (32 rows x 128)
  const int tid = threadIdx.x, lane = tid & 63, w = tid >> 6;
  const int l15 = lane & 15, lhi = lane >> 4;
  const int n0 = blockIdx.x * 128;

  // stage B tile -> swizzled LDS [128 rows][1024B], byte ^= ((row&7)<<4)
#pragma unroll
  for(int i=0;i<32;i++){
    int cid = tid + 256*i;
    int row = cid >> 6, cc = cid & 63;
    bf16x8 v = *(const bf16x8*)(Wfct + (size_t)(n0 + row)*512 + cc*8);
    *(bf16x8*)((char*)Bs + row*1024 + ((cc*16) ^ ((row & 7) << 4))) = v;
  }
  float bias[8]; int lnv[4];
#pragma unroll
  for(int nf=0;nf<8;nf++){
    int n = n0 + nf*16 + l15;
    bias[nf] = (n < VV) ? bfc[n] : 0.f;
  }
#pragma unroll
  for(int r=0;r<4;r++) lnv[r] = lens[w*16 + lhi*4 + r];
  __syncthreads();
  const bool edge = (n0 + 128 > VV);

  for(int t=0;t<TT;t++){
    bf16x8 af[16];
    const unsigned short* pA = hs + (size_t)(t*64 + w*16 + l15)*512 + lhi*8;
#pragma unroll
    for(int i=0;i<16;i++) af[i] = *(const bf16x8*)(pA + i*32);
    f32x4 acc[8];
#pragma unroll
    for(int nf=0;nf<8;nf++) acc[nf] = f32x4{0.f,0.f,0.f,0.f};
#pragma unroll
    for(int i=0;i<16;i++){
      int kb2 = i*64 + lhi*16;
#pragma unroll
      for(int nf=0;nf<8;nf++){
        int gr = nf*16 + l15;
        bf16x8 bv = *(const bf16x8*)((char*)Bs + gr*1024 + (kb2 ^ ((gr & 7) << 4)));
        acc[nf] = MFMA(af[i], bv, acc[nf]);
      }
    }
    // epilogue: 2 rounds of 32 rows via et, aligned 512B runs
    for(int h=0; h<2; h++){
      __syncthreads();
      if((w >> 1) == h){
#pragma unroll
        for(int nf=0;nf<8;nf++){
#pragma unroll
          for(int r=0;r<4;r++){
            bool valid = t < lnv[r];
            float v = valid ? (acc[nf][r] + bias[nf]) : 0.f;
            et[((w & 1)*16 + lhi*4 + r)*128 + nf*16 + l15] = v;
          }
        }
      }
      __syncthreads();
#pragma unroll
      for(int qq=0;qq<4;qq++){
        int idx = tid + 256*qq;
        int rowl = idx >> 5, c4 = idx & 31;
        int b = h*32 + rowl;
        const float* er = et + rowl*128;
        size_t bdw = (size_t)(b*20 + t)*VV + n0;
        if(!edge){
          int al = (int)((4 - (bdw & 3)) & 3);
          int chunks = (128 - al) >> 2;
          int tail = (128 - al) & 3;
          if(c4 < chunks){
            int s0 = al + c4*4;
            f32x4 v; v[0]=er[s0]; v[1]=er[s0+1]; v[2]=er[s0+2]; v[3]=er[s0+3];
            *(f32x4*)(out + bdw + s0) = v;
          }
          if(c4 < al) out[bdw + c4] = er[c4];
          if(c4 < tail){ int s1 = al + chunks*4 + c4; out[bdw + s1] = er[s1]; }
        } else {
#pragma unroll
          for(int i2=0;i2<4;i2++){
            int cg = n0 + c4*4 + i2;
            if(cg < VV) out[bdw + (c4*4 + i2)] = er[c4*4 + i2];
          }
        }
      }
    }
  }
}

// ---------- launcher ----------
extern "C" void kernel_launch(void* const* d_in, const int* in_sizes, int n_in,
                              void* d_out, int out_size, void* d_ws, size_t ws_size,
                              hipStream_t stream){
  const float* feat  = (const float*)d_in[0];
  const int*   cap   = (const int*)  d_in[1];
  const int*   lens  = (const int*)  d_in[2];
  const float* emb   = (const float*)d_in[3];
  const float* Wih   = (const float*)d_in[4];
  const float* Whh   = (const float*)d_in[5];
  const float* bih   = (const float*)d_in[6];
  const float* bhh   = (const float*)d_in[7];
  // d_in[8..13]: attention weights -- dead (enc seq len == 1)
  const float* Whi   = (const float*)d_in[14];
  const float* bhi   = (const float*)d_in[15];
  const float* Wci   = (const float*)d_in[16];
  const float* bci   = (const float*)d_in[17];
  const float* Wbeta = (const float*)d_in[18];
  const float* bbeta = (const float*)d_in[19];
  const float* Wfc   = (const float*)d_in[20];
  const float* bfc   = (const float*)d_in[21];
  float* out = (float*)d_out;

  char* ws = (char*)d_ws;
  size_t off = 0;
  auto alloc = [&](size_t bytes)->void*{
    void* p = ws + off; off += (bytes + 1023) & ~(size_t)1023; return p; };
  unsigned short* Wcomb  = (unsigned short*)alloc((size_t)2048*1024*2);
  unsigned short* We     = (unsigned short*)alloc((size_t)2048*512*2);
  unsigned short* Wbt    = (unsigned short*)alloc((size_t)512*512*2);
  unsigned short* Wfct   = (unsigned short*)alloc((size_t)VP*512*2);
  unsigned short* EmbMat = (unsigned short*)alloc((size_t)1280*512*2);
  float*          E4     = (float*)alloc((size_t)1280*2048*4);
  unsigned short* xbuf   = (unsigned short*)alloc((size_t)64*512*2);
  unsigned short* awbuf  = (unsigned short*)alloc((size_t)64*512*2);
  float*          cbuf   = (float*)alloc((size_t)64*512*4);
  unsigned short* hs     = (unsigned short*)alloc((size_t)1280*512*2);
  unsigned int*   ctrs   = (unsigned int*)alloc(256);

  static_cast<void>(hipFuncSetAttribute((const void*)recur,
      hipFuncAttributeMaxDynamicSharedMemorySize, 147456));
  static_cast<void>(hipFuncSetAttribute((const void*)outgemm,
      hipFuncAttributeMaxDynamicSharedMemorySize, 147456));

  hipMemsetAsync(ctrs, 0, 256, stream);

  // merged prep: cvt_weights | Wbeta^T | embeddings | h0/c0
  prep<<<3456, 256, 0, stream>>>(Wih, Whh, Wcomb, We, Wbeta, Wbt, feat, emb,
                                 cap, EmbMat, Whi, bhi, Wci, bci, xbuf, cbuf);

  // E4 = emb-part of gates + b_ih + b_hh (gate-minor): M=1280, N=2048, K=512
  gemmE<<<160, 256, 0, stream>>>(EmbMat, We, bih, bhh, E4, 10);

  // single-XCD recurrence + ticketed Wfc transpose
  recur<<<2080, 256, 147456, stream>>>(Wcomb, Wbt, bbeta, feat, E4, cbuf, lens,
                                       xbuf, awbuf, hs, ctrs, Wfc, Wfct);

  // B-stationary preds GEMM: 393 blocks, one n-tile each, all t
  outgemm<<<393, 256, 147456, stream>>>(hs, Wfct, bfc, lens, out);
}

// Round 14
// 648.172 us; speedup vs baseline: 1.0019x; 1.0019x over previous
//
#include <hip/hip_runtime.h>
#include <hip/hip_bf16.h>

// DecoderRNN: attention degenerate (enc seq len == 1 -> awe == gate*features).
// R14: R13 post-mortem found recur's 300us was the EMBEDDED Wfc transpose
//   (103+52MB at 450GB/s, 1 blk/CU latency-bound) -- not the worker fabric
//   (why R8/R9 fabric changes were null). Fixes:
//   (1) Wfc transpose -> standalone high-occupancy kernel (16.6KB LDS).
//   (2) recur = 32 workers only; non-XCD0 blocks run a bounded VALU filler
//       (holds clocks high; exits on done-flag or timeout).
//   (3) outgemm BN=64 (72KB LDS -> 2 blocks/CU, 786 blocks).

#define VV 50257
#define VP 50304    // 786*64
#define TT 20
#define NWRK 32

typedef __attribute__((ext_vector_type(4))) float f32x4;
typedef __attribute__((ext_vector_type(8))) short bf16x8;

#define MFMA(a,b,c) __builtin_amdgcn_mfma_f32_16x16x32_bf16((a),(b),(c),0,0,0)

__device__ __forceinline__ unsigned short f2bf(float f){
  union { float f; unsigned int u; } v; v.f = f;
  unsigned int u = v.u;
  return (unsigned short)((u + 0x7FFFu + ((u >> 16) & 1u)) >> 16);
}
__device__ __forceinline__ float sigf(float x){ return 1.f/(1.f + expf(-x)); }

__device__ __forceinline__ void gload_lds16(const unsigned short* g, unsigned short* l){
  __builtin_amdgcn_global_load_lds(
      (const __attribute__((address_space(1))) unsigned int*)g,
      (__attribute__((address_space(3))) unsigned int*)l, 16, 0, 0);
}

// ---- device-coherent accessors (sc0 sc1 on every cross-block access) ----
__device__ __forceinline__ void co_load16(bf16x8* d, const unsigned short* p){
  asm volatile("global_load_dwordx4 %0, %1, off sc0 sc1" : "=v"(*d) : "v"(p));
}
__device__ __forceinline__ void co_store2(unsigned short* p, unsigned short v){
  asm volatile("global_store_short %0, %1, off sc0 sc1" :: "v"(p), "v"(v) : "memory");
}
__device__ __forceinline__ unsigned int co_load_u32(const unsigned int* p){
  unsigned int r;
  asm volatile("global_load_dword %0, %1, off sc0 sc1\n\ts_waitcnt vmcnt(0)"
               : "=v"(r) : "v"(p) : "memory");
  return r;
}
__device__ __forceinline__ void co_store_u32(unsigned int* p, unsigned int v){
  asm volatile("global_store_dword %0, %1, off sc0 sc1" :: "v"(p), "v"(v) : "memory");
}

// flag barrier among the NWRK workers
__device__ __forceinline__ void gbar(unsigned int* flags, int widx, unsigned target){
  asm volatile("s_waitcnt vmcnt(0)" ::: "memory");
  __syncthreads();
  if(threadIdx.x == 0){
    co_store_u32(flags + widx, target);
  }
  if(threadIdx.x < 64){
    const unsigned int* p = flags + (threadIdx.x & 31);
    for(;;){
      unsigned v = co_load_u32(p);
      if(__all((int)(v >= target))) break;
      __builtin_amdgcn_s_sleep(1);
    }
  }
  __syncthreads();
}

// ---------- merged prep kernel ----------
// [0,2048): cvt_weights | [2048,2112): Wbeta^T | [2112,3392): emb | [3392,3456): h0/c0
__global__ __launch_bounds__(256) void prep(const float* __restrict__ Wih,
    const float* __restrict__ Whh, unsigned short* __restrict__ Wcomb,
    unsigned short* __restrict__ We,
    const float* __restrict__ Wbeta, unsigned short* __restrict__ Wbt,
    const float* __restrict__ feat, const float* __restrict__ emb,
    const int* __restrict__ cap, unsigned short* __restrict__ EmbMat,
    const float* __restrict__ Whi, const float* __restrict__ bhi,
    const float* __restrict__ Wci, const float* __restrict__ bci,
    unsigned short* __restrict__ xbuf, float* __restrict__ cbuf){
  __shared__ float tile[64][65];
  const int blk = blockIdx.x, tid = threadIdx.x;
  if(blk < 2048){
    int j = blk;
    for(int q=0;q<4;q++){ int k = tid + 256*q;
      float v = (k < 512) ? Whh[j*512 + k] : Wih[j*1024 + k];
      Wcomb[(size_t)j*1024 + k] = f2bf(v); }
    for(int q=0;q<2;q++){ int k = tid + 256*q;
      We[(size_t)j*512 + k] = f2bf(Wih[j*1024 + k]); }
  } else if(blk < 2112){
    int tb = blk - 2048;
    int c0 = (tb & 7)*64, r0 = (tb >> 3)*64;
    int tx = tid & 63, ty = tid >> 6;
    for(int i=0;i<16;i++){
      int r = ty + i*4;
      tile[r][tx] = Wbeta[(size_t)(r0+r)*512 + c0 + tx];
    }
    __syncthreads();
    for(int i=0;i<16;i++){
      int cl = ty + i*4;
      Wbt[(size_t)(c0+cl)*512 + r0 + tx] = f2bf(tile[tx][cl]);
    }
  } else if(blk < 3392){
    int m = blk - 2112; int t = m >> 6, b = m & 63;
    const float* src = (t == 0) ? (feat + b*512) : (emb + (size_t)cap[b*19 + (t-1)]*512);
    for(int q=0;q<2;q++){ int k = tid + 256*q;
      EmbMat[(size_t)m*512 + k] = f2bf(src[k]); }
  } else {
    int b = blk - 3392;
    float ah0 = bhi[tid], ah1 = bhi[tid+256];
    float ac0 = bci[tid], ac1 = bci[tid+256];
    for(int k=0;k<512;k++){
      float f = feat[b*512 + k];
      ah0 += f * Whi[k*512 + tid];     ah1 += f * Whi[k*512 + tid + 256];
      ac0 += f * Wci[k*512 + tid];     ac1 += f * Wci[k*512 + tid + 256];
    }
    xbuf[b*512 + tid] = f2bf(ah0);  xbuf[b*512 + tid + 256] = f2bf(ah1);
    cbuf[b*512 + tid] = ac0;        cbuf[b*512 + tid + 256] = ac1;
  }
}

// ---------- Wfc transpose: standalone, high occupancy (16.6KB static LDS) ----------
__global__ __launch_bounds__(256) void tpose(const float* __restrict__ src,
    unsigned short* __restrict__ dst){
  __shared__ float tile[64][65];
  int c0 = blockIdx.x*64, r0 = blockIdx.y*64;
  int tx = threadIdx.x & 63, ty = threadIdx.x >> 6;
  for(int i=0;i<16;i++){
    int r = ty + i*4; int sc = c0 + tx;
    tile[r][tx] = (sc < VV) ? src[(size_t)(r0+r)*VV + sc] : 0.f;
  }
  __syncthreads();
  for(int i=0;i<16;i++){
    int cl = ty + i*4;
    dst[(size_t)(c0+cl)*512 + r0 + tx] = f2bf(tile[tx][cl]);
  }
}

// ---------- 128x128 NT MFMA GEMM, K=512: E4 (gate-minor) ----------
__global__ __launch_bounds__(256) void gemmE(const unsigned short* __restrict__ Abf,
    const unsigned short* __restrict__ Bbf, const float* __restrict__ bias1,
    const float* __restrict__ bias2, float* __restrict__ Cout, int MT){
  __shared__ __align__(16) unsigned short As[128*64];
  __shared__ __align__(16) unsigned short Bs[128*64];
  const int nwg = gridDim.x;
  const int id = blockIdx.x;
  const int q = nwg >> 3, rr = nwg & 7;
  const int xcd = id & 7, pos = id >> 3;
  const int work = (xcd < rr) ? (xcd*(q+1) + pos) : (rr*(q+1) + (xcd-rr)*q + pos);
  const int m0 = (work % MT) * 128;
  const int n0 = (work / MT) * 128;
  const int tid = threadIdx.x, lane = tid & 63, w = tid >> 6;
  const int wr = w >> 1, wc = w & 1;
  const int lrow = lane >> 3, lcol = (lane & 7) * 8;
  const int l15 = lane & 15, lhi = lane >> 4;

  f32x4 acc[4][4];
#pragma unroll
  for(int i=0;i<4;i++)
#pragma unroll
    for(int j=0;j<4;j++) acc[i][j] = f32x4{0.f,0.f,0.f,0.f};

  for(int k0=0;k0<512;k0+=64){
    __syncthreads();
#pragma unroll
    for(int i=0;i<4;i++){
      int c = w*4 + i;
      int row = c*8 + lrow;
      gload_lds16(Abf + (size_t)(m0+row)*512 + k0 + lcol, As + c*512);
      gload_lds16(Bbf + (size_t)(n0+row)*512 + k0 + lcol, Bs + c*512);
    }
    asm volatile("s_waitcnt vmcnt(0)" ::: "memory");
    __syncthreads();
#pragma unroll
    for(int kk=0;kk<64;kk+=32){
      bf16x8 af[4], bfv[4];
#pragma unroll
      for(int mf=0;mf<4;mf++)
        af[mf] = *(const bf16x8*)(As + (wr*64 + mf*16 + l15)*64 + kk + lhi*8);
#pragma unroll
      for(int nf=0;nf<4;nf++)
        bfv[nf] = *(const bf16x8*)(Bs + (wc*64 + nf*16 + l15)*64 + kk + lhi*8);
#pragma unroll
      for(int mf=0;mf<4;mf++)
#pragma unroll
        for(int nf=0;nf<4;nf++)
          acc[mf][nf] = MFMA(af[mf], bfv[nf], acc[mf][nf]);
    }
  }
#pragma unroll
  for(int mf=0;mf<4;mf++)
#pragma unroll
    for(int nf=0;nf<4;nf++){
      int n = n0 + wc*64 + nf*16 + l15;
#pragma unroll
      for(int r=0;r<4;r++){
        int m = m0 + wr*64 + mf*16 + lhi*4 + r;
        int gate = n >> 9, col = n & 511;
        Cout[((size_t)m*512 + col)*4 + gate] = acc[mf][nf][r] + bias1[n] + bias2[n];
      }
    }
}

// ---------- single-XCD persistent recurrence (workers only + clock filler) ----------
// ctrs: [0]=worker ticket, [3]=done flag, [32..63]=flags
__global__ __launch_bounds__(256) void recur(
    const unsigned short* __restrict__ Wcomb,  // [2048][1024] bf16
    const unsigned short* __restrict__ Wbt,    // [512][512] bf16 (W_beta^T)
    const float* __restrict__ bbeta,
    const float* __restrict__ feat,            // [64][512] f32
    const float* __restrict__ E4,              // gate-minor f32
    const float* __restrict__ c0,
    const int* __restrict__ lens,
    unsigned short* xbuf,                      // [64][512] bf16 h
    unsigned short* awbuf,                     // [64][512] bf16 awe
    unsigned short* __restrict__ hs,           // [t*64+b][512] bf16
    unsigned int* ctrs){
  extern __shared__ char LDS[];
  char* WCb = LDS;            // 131072
  char* WBb = LDS + 131072;   // 16384
  int* lsh = (int*)LDS;
  const int tid = threadIdx.x;

  if(tid == 0){
    unsigned xcc = 99;
    asm volatile("s_getreg_b32 %0, hwreg(HW_REG_XCC_ID)" : "=s"(xcc));
    unsigned my = 0xffffffffu;
    if(xcc == 0) my = atomicAdd(&ctrs[0], 1u);
    lsh[0] = (my < NWRK) ? 1 : 0;
    lsh[1] = (int)my;
  }
  __syncthreads();
  const int iswork = lsh[0];
  const int widx = lsh[1];
  __syncthreads();

  if(!iswork){
    // ---- clock filler: VALU burn until workers done (or bounded timeout) ----
    float x = 1.0f + (float)tid;
    for(int it=0; it<6000; ++it){
#pragma unroll
      for(int u=0; u<64; ++u) x = __builtin_fmaf(x, 1.0000001f, 1e-7f);
      if((it & 63) == 0){
        if(co_load_u32(&ctrs[3]) != 0) break;
      }
    }
    asm volatile("" :: "v"(x));   // keep the burn live (rule #17)
    return;
  }

  // ---- worker ----
  const int lane = tid & 63, w = tid >> 6;
  const int l15 = lane & 15, lhi = lane >> 4;
  const int jj0 = widx * 16;
  const int jj = jj0 + l15;
  const int arow = w*16 + l15;
  unsigned int* flags = &ctrs[32];

  for(int cid = tid; cid < 8192; cid += 256){
    int gr = cid >> 7, cc = cid & 127;
    size_t g = (size_t)(gr >> 4)*512 + jj0 + (gr & 15);
    bf16x8 v = *(const bf16x8*)(Wcomb + g*1024 + cc*8);
    *(bf16x8*)(WCb + gr*2048 + ((cc*16) ^ ((gr & 7) << 4))) = v;
  }
  for(int cid = tid; cid < 1024; cid += 256){
    int r = cid >> 6, cc = cid & 63;
    bf16x8 v = *(const bf16x8*)(Wbt + (size_t)(jj0 + r)*512 + cc*8);
    *(bf16x8*)(WBb + r*1024 + ((cc*16) ^ ((r & 7) << 4))) = v;
  }

  float c_reg[4], fe[4]; int ln[4]; unsigned short hold[4];
#pragma unroll
  for(int r=0;r<4;r++){
    int b = w*16 + lhi*4 + r;
    c_reg[r] = c0[b*512 + jj];
    fe[r]    = feat[b*512 + jj];
    ln[r]    = lens[b];
    hold[r]  = xbuf[b*512 + jj];
  }
  const float bb = bbeta[jj];
  const unsigned short* pAx = xbuf  + (size_t)arow*512 + lhi*8;
  const unsigned short* pAw = awbuf + (size_t)arow*512 + lhi*8;
  __syncthreads();

  for(int t=0;t<TT;t++){
    // E4 prefetch
    f32x4 e4v[4];
#pragma unroll
    for(int r=0;r<4;r++){
      int b = w*16 + lhi*4 + r;
      e4v[r] = *(const f32x4*)(E4 + (((size_t)(t*64 + b))*512 + jj)*4);
    }
    // ---- phase 1: h -> beta + gates-h ----
    bf16x8 a[16];
#pragma unroll
    for(int i=0;i<16;i++) co_load16(&a[i], pAx + i*32);
    asm volatile("s_waitcnt vmcnt(0)" ::: "memory");
    __builtin_amdgcn_sched_barrier(0);

    f32x4 acca = f32x4{0.f,0.f,0.f,0.f};
    f32x4 accg[4];
#pragma unroll
    for(int i=0;i<4;i++) accg[i] = f32x4{0.f,0.f,0.f,0.f};
#pragma unroll
    for(int i=0;i<16;i++){
      int kb2 = i*64 + lhi*16;
      bf16x8 wb = *(const bf16x8*)(WBb + l15*1024 + (kb2 ^ ((l15 & 7) << 4)));
      acca = MFMA(a[i], wb, acca);
#pragma unroll
      for(int nf=0; nf<4; nf++){
        int gr = nf*16 + l15;
        bf16x8 wg = *(const bf16x8*)(WCb + gr*2048 + (kb2 ^ ((gr & 7) << 4)));
        accg[nf] = MFMA(a[i], wg, accg[nf]);
      }
    }
#pragma unroll
    for(int r=0;r<4;r++){
      int b = w*16 + lhi*4 + r;
      float g = sigf(acca[r] + bb);
      co_store2(awbuf + b*512 + jj, f2bf(g * fe[r]));
    }
    gbar(flags, widx, (unsigned)(2*t+1));

    // ---- phase 2: awe -> gates-awe ----
#pragma unroll
    for(int i=0;i<16;i++) co_load16(&a[i], pAw + i*32);
    asm volatile("s_waitcnt vmcnt(0)" ::: "memory");
    __builtin_amdgcn_sched_barrier(0);
#pragma unroll
    for(int i=0;i<16;i++){
      int kb2 = 1024 + i*64 + lhi*16;
#pragma unroll
      for(int nf=0; nf<4; nf++){
        int gr = nf*16 + l15;
        bf16x8 wg = *(const bf16x8*)(WCb + gr*2048 + (kb2 ^ ((gr & 7) << 4)));
        accg[nf] = MFMA(a[i], wg, accg[nf]);
      }
    }

    // ---- fused LSTM epilogue ----
#pragma unroll
    for(int r=0;r<4;r++){
      int b = w*16 + lhi*4 + r;
      float iv = sigf(accg[0][r] + e4v[r][0]);
      float fv = sigf(accg[1][r] + e4v[r][1]);
      float gv = tanhf(accg[2][r] + e4v[r][2]);
      float ov = sigf(accg[3][r] + e4v[r][3]);
      float cn = fv*c_reg[r] + iv*gv;
      float hn = ov * tanhf(cn);
      bool valid = t < ln[r];
      if(valid) c_reg[r] = cn;
      unsigned short hb = valid ? f2bf(hn) : hold[r];
      hold[r] = hb;
      hs[((size_t)(t*64 + b))*512 + jj] = hb;     // plain store; outgemm is a later kernel
      co_store2(xbuf + b*512 + jj, hb);
    }
    if(t < TT-1) gbar(flags, widx, (unsigned)(2*t+2));
  }
  if(tid == 0 && widx == 0) co_store_u32(&ctrs[3], 1u);   // release fillers
}

// ---------- B-stationary preds GEMM: BN=64, 2 blocks/CU ----------
// Stage 64KB Wfct n-tile -> swizzled LDS once; per t: A = hs slice (L2-hot),
// 64 MFMA/wave, aligned-run epilogue.
__global__ __launch_bounds__(256) void outgemm(
    const unsigned short* __restrict__ hs,     // [t*64+b][512] bf16
    const unsigned short* __restrict__ Wfct,   // [VP][512] bf16
    const float* __restrict__ bfc, const int* __restrict__ lens,
    float* __restrict__ out){
  extern __shared__ char LDS[];
  unsigned short* Bs = (unsigned short*)LDS;    // 65536 swizzled
  float* et = (float*)(LDS + 65536);            // 8192 (32 rows x 64)
  const int tid = threadIdx.x, lane = tid & 63, w = tid >> 6;
  const int l15 = lane & 15, lhi = lane >> 4;
  const int n0 = blockIdx.x * 64;

  // stage B: 64 rows x 512 cols, byte ^= ((row&7)<<4)
#pragma unroll
  for(int i=0;i<16;i++){
    int cid = tid + 256*i;
    int row = cid >> 6, cc = cid & 63;
    bf16x8 v = *(const bf16x8*)(Wfct + (size_t)(n0 + row)*512 + cc*8);
    *(bf16x8*)((char*)Bs + row*1024 + ((cc*16) ^ ((row & 7) << 4))) = v;
  }
  float bias[4]; int lnv[4];
#pragma unroll
  for(int nf=0;nf<4;nf++){
    int n = n0 + nf*16 + l15;
    bias[nf] = (n < VV) ? bfc[n] : 0.f;
  }
#pragma unroll
  for(int r=0;r<4;r++) lnv[r] = lens[w*16 + lhi*4 + r];
  __syncthreads();
  const bool edge = (n0 + 64 > VV);

  for(int t=0;t<TT;t++){
    bf16x8 af[16];
    const unsigned short* pA = hs + (size_t)(t*64 + w*16 + l15)*512 + lhi*8;
#pragma unroll
    for(int i=0;i<16;i++) af[i] = *(const bf16x8*)(pA + i*32);
    f32x4 acc[4];
#pragma unroll
    for(int nf=0;nf<4;nf++) acc[nf] = f32x4{0.f,0.f,0.f,0.f};
#pragma unroll
    for(int i=0;i<16;i++){
      int kb2 = i*64 + lhi*16;
#pragma unroll
      for(int nf=0;nf<4;nf++){
        int gr = nf*16 + l15;
        bf16x8 bv = *(const bf16x8*)((char*)Bs + gr*1024 + (kb2 ^ ((gr & 7) << 4)));
        acc[nf] = MFMA(af[i], bv, acc[nf]);
      }
    }
    // epilogue: 2 rounds of 32 rows via et, aligned runs (256B/row)
    for(int h=0; h<2; h++){
      __syncthreads();
      if((w >> 1) == h){
#pragma unroll
        for(int nf=0;nf<4;nf++){
#pragma unroll
          for(int r=0;r<4;r++){
            bool valid = t < lnv[r];
            float v = valid ? (acc[nf][r] + bias[nf]) : 0.f;
            et[((w & 1)*16 + lhi*4 + r)*64 + nf*16 + l15] = v;
          }
        }
      }
      __syncthreads();
#pragma unroll
      for(int qq=0;qq<2;qq++){
        int idx = tid + 256*qq;
        int rowl = idx >> 4, c4 = idx & 15;
        int b = h*32 + rowl;
        const float* er = et + rowl*64;
        size_t bdw = (size_t)(b*20 + t)*VV + n0;
        if(!edge){
          int al = (int)((4 - (bdw & 3)) & 3);
          int chunks = (64 - al) >> 2;
          int tail = (64 - al) & 3;
          if(c4 < chunks){
            int s0 = al + c4*4;
            f32x4 v; v[0]=er[s0]; v[1]=er[s0+1]; v[2]=er[s0+2]; v[3]=er[s0+3];
            *(f32x4*)(out + bdw + s0) = v;
          }
          if(c4 < al) out[bdw + c4] = er[c4];
          if(c4 < tail){ int s1 = al + chunks*4 + c4; out[bdw + s1] = er[s1]; }
        } else {
#pragma unroll
          for(int i2=0;i2<4;i2++){
            int cg = n0 + c4*4 + i2;
            if(cg < VV) out[bdw + (c4*4 + i2)] = er[c4*4 + i2];
          }
        }
      }
    }
  }
}

// ---------- launcher ----------
extern "C" void kernel_launch(void* const* d_in, const int* in_sizes, int n_in,
                              void* d_out, int out_size, void* d_ws, size_t ws_size,
                              hipStream_t stream){
  const float* feat  = (const float*)d_in[0];
  const int*   cap   = (const int*)  d_in[1];
  const int*   lens  = (const int*)  d_in[2];
  const float* emb   = (const float*)d_in[3];
  const float* Wih   = (const float*)d_in[4];
  const float* Whh   = (const float*)d_in[5];
  const float* bih   = (const float*)d_in[6];
  const float* bhh   = (const float*)d_in[7];
  // d_in[8..13]: attention weights -- dead (enc seq len == 1)
  const float* Whi   = (const float*)d_in[14];
  const float* bhi   = (const float*)d_in[15];
  const float* Wci   = (const float*)d_in[16];
  const float* bci   = (const float*)d_in[17];
  const float* Wbeta = (const float*)d_in[18];
  const float* bbeta = (const float*)d_in[19];
  const float* Wfc   = (const float*)d_in[20];
  const float* bfc   = (const float*)d_in[21];
  float* out = (float*)d_out;

  char* ws = (char*)d_ws;
  size_t off = 0;
  auto alloc = [&](size_t bytes)->void*{
    void* p = ws + off; off += (bytes + 1023) & ~(size_t)1023; return p; };
  unsigned short* Wcomb  = (unsigned short*)alloc((size_t)2048*1024*2);
  unsigned short* We     = (unsigned short*)alloc((size_t)2048*512*2);
  unsigned short* Wbt    = (unsigned short*)alloc((size_t)512*512*2);
  unsigned short* Wfct   = (unsigned short*)alloc((size_t)VP*512*2);
  unsigned short* EmbMat = (unsigned short*)alloc((size_t)1280*512*2);
  float*          E4     = (float*)alloc((size_t)1280*2048*4);
  unsigned short* xbuf   = (unsigned short*)alloc((size_t)64*512*2);
  unsigned short* awbuf  = (unsigned short*)alloc((size_t)64*512*2);
  float*          cbuf   = (float*)alloc((size_t)64*512*4);
  unsigned short* hs     = (unsigned short*)alloc((size_t)1280*512*2);
  unsigned int*   ctrs   = (unsigned int*)alloc(256);

  static_cast<void>(hipFuncSetAttribute((const void*)recur,
      hipFuncAttributeMaxDynamicSharedMemorySize, 147456));
  static_cast<void>(hipFuncSetAttribute((const void*)outgemm,
      hipFuncAttributeMaxDynamicSharedMemorySize, 73728));

  hipMemsetAsync(ctrs, 0, 256, stream);

  // merged prep: cvt_weights | Wbeta^T | embeddings | h0/c0
  prep<<<3456, 256, 0, stream>>>(Wih, Whh, Wcomb, We, Wbeta, Wbt, feat, emb,
                                 cap, EmbMat, Whi, bhi, Wci, bci, xbuf, cbuf);

  // Wfc transpose: standalone, high occupancy
  tpose<<<dim3(786,8), 256, 0, stream>>>(Wfc, Wfct);

  // E4 = emb-part of gates + b_ih + b_hh (gate-minor): M=1280, N=2048, K=512
  gemmE<<<160, 256, 0, stream>>>(EmbMat, We, bih, bhh, E4, 10);

  // single-XCD recurrence (32 workers) + clock filler on remaining CUs
  recur<<<256, 256, 147456, stream>>>(Wcomb, Wbt, bbeta, feat, E4, cbuf, lens,
                                      xbuf, awbuf, hs, ctrs);

  // B-stationary preds GEMM: 786 blocks, one 64-wide n-tile each, all t
  outgemm<<<786, 256, 73728, stream>>>(hs, Wfct, bfc, lens, out);
}

// Round 15
// 566.510 us; speedup vs baseline: 1.1464x; 1.1442x over previous
//
#include <hip/hip_runtime.h>
#include <hip/hip_bf16.h>

// DecoderRNN: attention degenerate (enc seq len == 1 -> awe == gate*features).
// R15: R14 proved recur's 300us is pure sync-hop cost (40 hops x ~7.5us,
//   invariant across all fabrics) -> embedded tpose was FREE in R9 (hidden
//   under barrier waits); R13/R14 regressed paying it separately. Structure:
//   R13 skeleton (recur + embedded ticketed tpose). New outgemm: BN=64,
//   VALID-WAVE SKIP (lengths sorted descending -> step-t valid rows are a
//   prefix; waves with all rows len<=t skip loads+MFMA, store zeros) and
//   NONTEMPORAL f32x4 stores (full-line runs -> bypass L2 write-allocate).

#define VV 50257
#define VP 50304    // 786*64
#define TT 20
#define NWRK 32
#define NTILES 6288 // 786 * 8 transpose tiles

typedef __attribute__((ext_vector_type(4))) float f32x4;
typedef __attribute__((ext_vector_type(8))) short bf16x8;

#define MFMA(a,b,c) __builtin_amdgcn_mfma_f32_16x16x32_bf16((a),(b),(c),0,0,0)

__device__ __forceinline__ unsigned short f2bf(float f){
  union { float f; unsigned int u; } v; v.f = f;
  unsigned int u = v.u;
  return (unsigned short)((u + 0x7FFFu + ((u >> 16) & 1u)) >> 16);
}
__device__ __forceinline__ float sigf(float x){ return 1.f/(1.f + expf(-x)); }

__device__ __forceinline__ void gload_lds16(const unsigned short* g, unsigned short* l){
  __builtin_amdgcn_global_load_lds(
      (const __attribute__((address_space(1))) unsigned int*)g,
      (__attribute__((address_space(3))) unsigned int*)l, 16, 0, 0);
}

// ---- device-coherent accessors (sc0 sc1 on every cross-block access) ----
__device__ __forceinline__ void co_load16(bf16x8* d, const unsigned short* p){
  asm volatile("global_load_dwordx4 %0, %1, off sc0 sc1" : "=v"(*d) : "v"(p));
}
__device__ __forceinline__ void co_store2(unsigned short* p, unsigned short v){
  asm volatile("global_store_short %0, %1, off sc0 sc1" :: "v"(p), "v"(v) : "memory");
}
__device__ __forceinline__ unsigned int co_load_u32(const unsigned int* p){
  unsigned int r;
  asm volatile("global_load_dword %0, %1, off sc0 sc1\n\ts_waitcnt vmcnt(0)"
               : "=v"(r) : "v"(p) : "memory");
  return r;
}
__device__ __forceinline__ void co_store_u32(unsigned int* p, unsigned int v){
  asm volatile("global_store_dword %0, %1, off sc0 sc1" :: "v"(p), "v"(v) : "memory");
}

// flag barrier among the NWRK workers
__device__ __forceinline__ void gbar(unsigned int* flags, int widx, unsigned target){
  asm volatile("s_waitcnt vmcnt(0)" ::: "memory");
  __syncthreads();
  if(threadIdx.x == 0){
    co_store_u32(flags + widx, target);
  }
  if(threadIdx.x < 64){
    const unsigned int* p = flags + (threadIdx.x & 31);
    for(;;){
      unsigned v = co_load_u32(p);
      if(__all((int)(v >= target))) break;
      __builtin_amdgcn_s_sleep(1);
    }
  }
  __syncthreads();
}

// ---------- merged prep kernel ----------
// [0,2048): cvt_weights | [2048,2112): Wbeta^T | [2112,3392): emb | [3392,3456): h0/c0
__global__ __launch_bounds__(256) void prep(const float* __restrict__ Wih,
    const float* __restrict__ Whh, unsigned short* __restrict__ Wcomb,
    unsigned short* __restrict__ We,
    const float* __restrict__ Wbeta, unsigned short* __restrict__ Wbt,
    const float* __restrict__ feat, const float* __restrict__ emb,
    const int* __restrict__ cap, unsigned short* __restrict__ EmbMat,
    const float* __restrict__ Whi, const float* __restrict__ bhi,
    const float* __restrict__ Wci, const float* __restrict__ bci,
    unsigned short* __restrict__ xbuf, float* __restrict__ cbuf){
  __shared__ float tile[64][65];
  const int blk = blockIdx.x, tid = threadIdx.x;
  if(blk < 2048){
    int j = blk;
    for(int q=0;q<4;q++){ int k = tid + 256*q;
      float v = (k < 512) ? Whh[j*512 + k] : Wih[j*1024 + k];
      Wcomb[(size_t)j*1024 + k] = f2bf(v); }
    for(int q=0;q<2;q++){ int k = tid + 256*q;
      We[(size_t)j*512 + k] = f2bf(Wih[j*1024 + k]); }
  } else if(blk < 2112){
    int tb = blk - 2048;
    int c0 = (tb & 7)*64, r0 = (tb >> 3)*64;
    int tx = tid & 63, ty = tid >> 6;
    for(int i=0;i<16;i++){
      int r = ty + i*4;
      tile[r][tx] = Wbeta[(size_t)(r0+r)*512 + c0 + tx];
    }
    __syncthreads();
    for(int i=0;i<16;i++){
      int cl = ty + i*4;
      Wbt[(size_t)(c0+cl)*512 + r0 + tx] = f2bf(tile[tx][cl]);
    }
  } else if(blk < 3392){
    int m = blk - 2112; int t = m >> 6, b = m & 63;
    const float* src = (t == 0) ? (feat + b*512) : (emb + (size_t)cap[b*19 + (t-1)]*512);
    for(int q=0;q<2;q++){ int k = tid + 256*q;
      EmbMat[(size_t)m*512 + k] = f2bf(src[k]); }
  } else {
    int b = blk - 3392;
    float ah0 = bhi[tid], ah1 = bhi[tid+256];
    float ac0 = bci[tid], ac1 = bci[tid+256];
    for(int k=0;k<512;k++){
      float f = feat[b*512 + k];
      ah0 += f * Whi[k*512 + tid];     ah1 += f * Whi[k*512 + tid + 256];
      ac0 += f * Wci[k*512 + tid];     ac1 += f * Wci[k*512 + tid + 256];
    }
    xbuf[b*512 + tid] = f2bf(ah0);  xbuf[b*512 + tid + 256] = f2bf(ah1);
    cbuf[b*512 + tid] = ac0;        cbuf[b*512 + tid + 256] = ac1;
  }
}

// ---------- 128x128 NT MFMA GEMM, K=512: E4 (gate-minor) ----------
__global__ __launch_bounds__(256) void gemmE(const unsigned short* __restrict__ Abf,
    const unsigned short* __restrict__ Bbf, const float* __restrict__ bias1,
    const float* __restrict__ bias2, float* __restrict__ Cout, int MT){
  __shared__ __align__(16) unsigned short As[128*64];
  __shared__ __align__(16) unsigned short Bs[128*64];
  const int nwg = gridDim.x;
  const int id = blockIdx.x;
  const int q = nwg >> 3, rr = nwg & 7;
  const int xcd = id & 7, pos = id >> 3;
  const int work = (xcd < rr) ? (xcd*(q+1) + pos) : (rr*(q+1) + (xcd-rr)*q + pos);
  const int m0 = (work % MT) * 128;
  const int n0 = (work / MT) * 128;
  const int tid = threadIdx.x, lane = tid & 63, w = tid >> 6;
  const int wr = w >> 1, wc = w & 1;
  const int lrow = lane >> 3, lcol = (lane & 7) * 8;
  const int l15 = lane & 15, lhi = lane >> 4;

  f32x4 acc[4][4];
#pragma unroll
  for(int i=0;i<4;i++)
#pragma unroll
    for(int j=0;j<4;j++) acc[i][j] = f32x4{0.f,0.f,0.f,0.f};

  for(int k0=0;k0<512;k0+=64){
    __syncthreads();
#pragma unroll
    for(int i=0;i<4;i++){
      int c = w*4 + i;
      int row = c*8 + lrow;
      gload_lds16(Abf + (size_t)(m0+row)*512 + k0 + lcol, As + c*512);
      gload_lds16(Bbf + (size_t)(n0+row)*512 + k0 + lcol, Bs + c*512);
    }
    asm volatile("s_waitcnt vmcnt(0)" ::: "memory");
    __syncthreads();
#pragma unroll
    for(int kk=0;kk<64;kk+=32){
      bf16x8 af[4], bfv[4];
#pragma unroll
      for(int mf=0;mf<4;mf++)
        af[mf] = *(const bf16x8*)(As + (wr*64 + mf*16 + l15)*64 + kk + lhi*8);
#pragma unroll
      for(int nf=0;nf<4;nf++)
        bfv[nf] = *(const bf16x8*)(Bs + (wc*64 + nf*16 + l15)*64 + kk + lhi*8);
#pragma unroll
      for(int mf=0;mf<4;mf++)
#pragma unroll
        for(int nf=0;nf<4;nf++)
          acc[mf][nf] = MFMA(af[mf], bfv[nf], acc[mf][nf]);
    }
  }
#pragma unroll
  for(int mf=0;mf<4;mf++)
#pragma unroll
    for(int nf=0;nf<4;nf++){
      int n = n0 + wc*64 + nf*16 + l15;
#pragma unroll
      for(int r=0;r<4;r++){
        int m = m0 + wr*64 + mf*16 + lhi*4 + r;
        int gate = n >> 9, col = n & 511;
        Cout[((size_t)m*512 + col)*4 + gate] = acc[mf][nf][r] + bias1[n] + bias2[n];
      }
    }
}

// ---------- single-XCD persistent recurrence + ticketed Wfc transpose ----------
// ctrs: [0]=worker tk, [16]=tp tk, [32..63]=flags
__global__ __launch_bounds__(256) void recur(
    const unsigned short* __restrict__ Wcomb,  // [2048][1024] bf16
    const unsigned short* __restrict__ Wbt,    // [512][512] bf16 (W_beta^T)
    const float* __restrict__ bbeta,
    const float* __restrict__ feat,            // [64][512] f32
    const float* __restrict__ E4,              // gate-minor f32
    const float* __restrict__ c0,
    const int* __restrict__ lens,
    unsigned short* xbuf,                      // [64][512] bf16 h
    unsigned short* awbuf,                     // [64][512] bf16 awe
    unsigned short* __restrict__ hs,           // [t*64+b][512] bf16
    unsigned int* ctrs,
    const float* __restrict__ Wfc, unsigned short* __restrict__ Wfct){
  extern __shared__ char LDS[];
  char* WCb = LDS;            // 131072
  char* WBb = LDS + 131072;   // 16384
  int* lsh = (int*)LDS;
  const int tid = threadIdx.x;

  if(tid == 0){
    unsigned xcc = 99;
    asm volatile("s_getreg_b32 %0, hwreg(HW_REG_XCC_ID)" : "=s"(xcc));
    unsigned my = 0xffffffffu;
    if(xcc == 0) my = atomicAdd(&ctrs[0], 1u);
    lsh[0] = (my < NWRK) ? 1 : 0;
    lsh[1] = (int)my;
  }
  __syncthreads();
  const int iswork = lsh[0];
  const int widx = lsh[1];
  __syncthreads();

  if(!iswork){
    // ---- Wfc transpose via ticket (hidden under worker barrier waits) ----
    float (*tile)[65] = (float(*)[65])LDS;
    int tx = tid & 63, ty = tid >> 6;
    for(;;){
      __syncthreads();
      if(tid == 0) lsh[0] = (int)atomicAdd(&ctrs[16], 1u);
      __syncthreads();
      int tb = lsh[0];
      __syncthreads();
      if(tb >= NTILES) return;
      int c0t = (tb % 786)*64, r0 = (tb / 786)*64;
      for(int i=0;i<16;i++){
        int r = ty + i*4; int sc = c0t + tx;
        tile[r][tx] = (sc < VV) ? Wfc[(size_t)(r0+r)*VV + sc] : 0.f;
      }
      __syncthreads();
      for(int i=0;i<16;i++){
        int cl = ty + i*4;
        Wfct[(size_t)(c0t+cl)*512 + r0 + tx] = f2bf(tile[tx][cl]);
      }
    }
  }

  // ---- worker ----
  const int lane = tid & 63, w = tid >> 6;
  const int l15 = lane & 15, lhi = lane >> 4;
  const int jj0 = widx * 16;
  const int jj = jj0 + l15;
  const int arow = w*16 + l15;
  unsigned int* flags = &ctrs[32];

  for(int cid = tid; cid < 8192; cid += 256){
    int gr = cid >> 7, cc = cid & 127;
    size_t g = (size_t)(gr >> 4)*512 + jj0 + (gr & 15);
    bf16x8 v = *(const bf16x8*)(Wcomb + g*1024 + cc*8);
    *(bf16x8*)(WCb + gr*2048 + ((cc*16) ^ ((gr & 7) << 4))) = v;
  }
  for(int cid = tid; cid < 1024; cid += 256){
    int r = cid >> 6, cc = cid & 63;
    bf16x8 v = *(const bf16x8*)(Wbt + (size_t)(jj0 + r)*512 + cc*8);
    *(bf16x8*)(WBb + r*1024 + ((cc*16) ^ ((r & 7) << 4))) = v;
  }

  float c_reg[4], fe[4]; int ln[4]; unsigned short hold[4];
#pragma unroll
  for(int r=0;r<4;r++){
    int b = w*16 + lhi*4 + r;
    c_reg[r] = c0[b*512 + jj];
    fe[r]    = feat[b*512 + jj];
    ln[r]    = lens[b];
    hold[r]  = xbuf[b*512 + jj];
  }
  const float bb = bbeta[jj];
  const unsigned short* pAx = xbuf  + (size_t)arow*512 + lhi*8;
  const unsigned short* pAw = awbuf + (size_t)arow*512 + lhi*8;
  __syncthreads();

  for(int t=0;t<TT;t++){
    // E4 prefetch
    f32x4 e4v[4];
#pragma unroll
    for(int r=0;r<4;r++){
      int b = w*16 + lhi*4 + r;
      e4v[r] = *(const f32x4*)(E4 + (((size_t)(t*64 + b))*512 + jj)*4);
    }
    // ---- phase 1: h -> beta + gates-h ----
    bf16x8 a[16];
#pragma unroll
    for(int i=0;i<16;i++) co_load16(&a[i], pAx + i*32);
    asm volatile("s_waitcnt vmcnt(0)" ::: "memory");
    __builtin_amdgcn_sched_barrier(0);

    f32x4 acca = f32x4{0.f,0.f,0.f,0.f};
    f32x4 accg[4];
#pragma unroll
    for(int i=0;i<4;i++) accg[i] = f32x4{0.f,0.f,0.f,0.f};
#pragma unroll
    for(int i=0;i<16;i++){
      int kb2 = i*64 + lhi*16;
      bf16x8 wb = *(const bf16x8*)(WBb + l15*1024 + (kb2 ^ ((l15 & 7) << 4)));
      acca = MFMA(a[i], wb, acca);
#pragma unroll
      for(int nf=0; nf<4; nf++){
        int gr = nf*16 + l15;
        bf16x8 wg = *(const bf16x8*)(WCb + gr*2048 + (kb2 ^ ((gr & 7) << 4)));
        accg[nf] = MFMA(a[i], wg, accg[nf]);
      }
    }
#pragma unroll
    for(int r=0;r<4;r++){
      int b = w*16 + lhi*4 + r;
      float g = sigf(acca[r] + bb);
      co_store2(awbuf + b*512 + jj, f2bf(g * fe[r]));
    }
    gbar(flags, widx, (unsigned)(2*t+1));

    // ---- phase 2: awe -> gates-awe ----
#pragma unroll
    for(int i=0;i<16;i++) co_load16(&a[i], pAw + i*32);
    asm volatile("s_waitcnt vmcnt(0)" ::: "memory");
    __builtin_amdgcn_sched_barrier(0);
#pragma unroll
    for(int i=0;i<16;i++){
      int kb2 = 1024 + i*64 + lhi*16;
#pragma unroll
      for(int nf=0; nf<4; nf++){
        int gr = nf*16 + l15;
        bf16x8 wg = *(const bf16x8*)(WCb + gr*2048 + (kb2 ^ ((gr & 7) << 4)));
        accg[nf] = MFMA(a[i], wg, accg[nf]);
      }
    }

    // ---- fused LSTM epilogue ----
#pragma unroll
    for(int r=0;r<4;r++){
      int b = w*16 + lhi*4 + r;
      float iv = sigf(accg[0][r] + e4v[r][0]);
      float fv = sigf(accg[1][r] + e4v[r][1]);
      float gv = tanhf(accg[2][r] + e4v[r][2]);
      float ov = sigf(accg[3][r] + e4v[r][3]);
      float cn = fv*c_reg[r] + iv*gv;
      float hn = ov * tanhf(cn);
      bool valid = t < ln[r];
      if(valid) c_reg[r] = cn;
      unsigned short hb = valid ? f2bf(hn) : hold[r];
      hold[r] = hb;
      hs[((size_t)(t*64 + b))*512 + jj] = hb;     // plain store; outgemm is a later kernel
      co_store2(xbuf + b*512 + jj, hb);
    }
    if(t < TT-1) gbar(flags, widx, (unsigned)(2*t+2));
  }
}

// ---------- B-stationary preds GEMM: BN=64, valid-wave skip, nt stores ----------
// lens sorted DESCENDING -> step-t valid rows are prefix [0, cnt_t). Wave w
// (rows 16w..16w+16): if lens[16w] <= t, skip A-loads+MFMA (store zeros only).
__global__ __launch_bounds__(256) void outgemm(
    const unsigned short* __restrict__ hs,     // [t*64+b][512] bf16
    const unsigned short* __restrict__ Wfct,   // [VP][512] bf16
    const float* __restrict__ bfc, const int* __restrict__ lens,
    float* __restrict__ out){
  extern __shared__ char LDS[];
  unsigned short* Bs = (unsigned short*)LDS;    // 65536 swizzled
  float* et = (float*)(LDS + 65536);            // 8192 (32 rows x 64)
  const int tid = threadIdx.x, lane = tid & 63, w = tid >> 6;
  const int l15 = lane & 15, lhi = lane >> 4;
  const int n0 = blockIdx.x * 64;

  // stage B: 64 rows x 512 cols, byte ^= ((row&7)<<4)
#pragma unroll
  for(int i=0;i<16;i++){
    int cid = tid + 256*i;
    int row = cid >> 6, cc = cid & 63;
    bf16x8 v = *(const bf16x8*)(Wfct + (size_t)(n0 + row)*512 + cc*8);
    *(bf16x8*)((char*)Bs + row*1024 + ((cc*16) ^ ((row & 7) << 4))) = v;
  }
  float bias[4]; int lnv[4];
#pragma unroll
  for(int nf=0;nf<4;nf++){
    int n = n0 + nf*16 + l15;
    bias[nf] = (n < VV) ? bfc[n] : 0.f;
  }
#pragma unroll
  for(int r=0;r<4;r++) lnv[r] = lens[w*16 + lhi*4 + r];
  const int wmax = lens[w*16];     // max len among wave's rows (descending order)
  __syncthreads();
  const bool edge = (n0 + 64 > VV);

  for(int t=0;t<TT;t++){
    f32x4 acc[4];
#pragma unroll
    for(int nf=0;nf<4;nf++) acc[nf] = f32x4{0.f,0.f,0.f,0.f};
    if(t < wmax){
      bf16x8 af[16];
      const unsigned short* pA = hs + (size_t)(t*64 + w*16 + l15)*512 + lhi*8;
#pragma unroll
      for(int i=0;i<16;i++) af[i] = *(const bf16x8*)(pA + i*32);
#pragma unroll
      for(int i=0;i<16;i++){
        int kb2 = i*64 + lhi*16;
#pragma unroll
        for(int nf=0;nf<4;nf++){
          int gr = nf*16 + l15;
          bf16x8 bv = *(const bf16x8*)((char*)Bs + gr*1024 + (kb2 ^ ((gr & 7) << 4)));
          acc[nf] = MFMA(af[i], bv, acc[nf]);
        }
      }
    }
    // epilogue: 2 rounds of 32 rows via et; nontemporal full-line stores
    for(int h=0; h<2; h++){
      __syncthreads();
      if((w >> 1) == h){
#pragma unroll
        for(int nf=0;nf<4;nf++){
#pragma unroll
          for(int r=0;r<4;r++){
            bool valid = t < lnv[r];
            float v = valid ? (acc[nf][r] + bias[nf]) : 0.f;
            et[((w & 1)*16 + lhi*4 + r)*64 + nf*16 + l15] = v;
          }
        }
      }
      __syncthreads();
#pragma unroll
      for(int qq=0;qq<2;qq++){
        int idx = tid + 256*qq;
        int rowl = idx >> 4, c4 = idx & 15;
        int b = h*32 + rowl;
        const float* er = et + rowl*64;
        size_t bdw = (size_t)(b*20 + t)*VV + n0;
        if(!edge){
          int al = (int)((4 - (bdw & 3)) & 3);
          int chunks = (64 - al) >> 2;
          int tail = (64 - al) & 3;
          if(c4 < chunks){
            int s0 = al + c4*4;
            f32x4 v; v[0]=er[s0]; v[1]=er[s0+1]; v[2]=er[s0+2]; v[3]=er[s0+3];
            __builtin_nontemporal_store(v, (f32x4*)(out + bdw + s0));
          }
          if(c4 < al) __builtin_nontemporal_store(er[c4], out + bdw + c4);
          if(c4 < tail){ int s1 = al + chunks*4 + c4;
            __builtin_nontemporal_store(er[s1], out + bdw + s1); }
        } else {
#pragma unroll
          for(int i2=0;i2<4;i2++){
            int cg = n0 + c4*4 + i2;
            if(cg < VV) __builtin_nontemporal_store(er[c4*4 + i2], out + bdw + (c4*4 + i2));
          }
        }
      }
    }
  }
}

// ---------- launcher ----------
extern "C" void kernel_launch(void* const* d_in, const int* in_sizes, int n_in,
                              void* d_out, int out_size, void* d_ws, size_t ws_size,
                              hipStream_t stream){
  const float* feat  = (const float*)d_in[0];
  const int*   cap   = (const int*)  d_in[1];
  const int*   lens  = (const int*)  d_in[2];
  const float* emb   = (const float*)d_in[3];
  const float* Wih   = (const float*)d_in[4];
  const float* Whh   = (const float*)d_in[5];
  const float* bih   = (const float*)d_in[6];
  const float* bhh   = (const float*)d_in[7];
  // d_in[8..13]: attention weights -- dead (enc seq len == 1)
  const float* Whi   = (const float*)d_in[14];
  const float* bhi   = (const float*)d_in[15];
  const float* Wci   = (const float*)d_in[16];
  const float* bci   = (const float*)d_in[17];
  const float* Wbeta = (const float*)d_in[18];
  const float* bbeta = (const float*)d_in[19];
  const float* Wfc   = (const float*)d_in[20];
  const float* bfc   = (const float*)d_in[21];
  float* out = (float*)d_out;

  char* ws = (char*)d_ws;
  size_t off = 0;
  auto alloc = [&](size_t bytes)->void*{
    void* p = ws + off; off += (bytes + 1023) & ~(size_t)1023; return p; };
  unsigned short* Wcomb  = (unsigned short*)alloc((size_t)2048*1024*2);
  unsigned short* We     = (unsigned short*)alloc((size_t)2048*512*2);
  unsigned short* Wbt    = (unsigned short*)alloc((size_t)512*512*2);
  unsigned short* Wfct   = (unsigned short*)alloc((size_t)VP*512*2);
  unsigned short* EmbMat = (unsigned short*)alloc((size_t)1280*512*2);
  float*          E4     = (float*)alloc((size_t)1280*2048*4);
  unsigned short* xbuf   = (unsigned short*)alloc((size_t)64*512*2);
  unsigned short* awbuf  = (unsigned short*)alloc((size_t)64*512*2);
  float*          cbuf   = (float*)alloc((size_t)64*512*4);
  unsigned short* hs     = (unsigned short*)alloc((size_t)1280*512*2);
  unsigned int*   ctrs   = (unsigned int*)alloc(256);

  static_cast<void>(hipFuncSetAttribute((const void*)recur,
      hipFuncAttributeMaxDynamicSharedMemorySize, 147456));
  static_cast<void>(hipFuncSetAttribute((const void*)outgemm,
      hipFuncAttributeMaxDynamicSharedMemorySize, 73728));

  hipMemsetAsync(ctrs, 0, 256, stream);

  // merged prep: cvt_weights | Wbeta^T | embeddings | h0/c0
  prep<<<3456, 256, 0, stream>>>(Wih, Whh, Wcomb, We, Wbeta, Wbt, feat, emb,
                                 cap, EmbMat, Whi, bhi, Wci, bci, xbuf, cbuf);

  // E4 = emb-part of gates + b_ih + b_hh (gate-minor): M=1280, N=2048, K=512
  gemmE<<<160, 256, 0, stream>>>(EmbMat, We, bih, bhh, E4, 10);

  // single-XCD recurrence + ticketed Wfc transpose (hidden under barrier waits)
  recur<<<2080, 256, 147456, stream>>>(Wcomb, Wbt, bbeta, feat, E4, cbuf, lens,
                                       xbuf, awbuf, hs, ctrs, Wfc, Wfct);

  // B-stationary preds GEMM: 786 blocks, one 64-wide n-tile each, all t
  outgemm<<<786, 256, 73728, stream>>>(hs, Wfct, bfc, lens, out);
}